// Round 1
// baseline (1793.604 us; speedup 1.0000x reference)
//
#include <hip/hip_runtime.h>

#define NN 100000
#define NE 1600000

typedef __attribute__((ext_vector_type(4))) float   fx4;
typedef __attribute__((ext_vector_type(4))) _Float16 hx4;

__device__ __forceinline__ float ftanh(float x) {
    // tanh(x) = 1 - 2/(exp(2x)+1); exp2-based, saturates correctly at +-inf
    float t = __expf(2.0f * x);
    return 1.0f - 2.0f * __builtin_amdgcn_rcpf(t + 1.0f);
}

#define MFMA(a, b, c) __builtin_amdgcn_mfma_f32_16x16x16f16((a), (b), (c), 0, 0, 0)

// ---------------------------------------------------------------------------
// Main per-iteration edge kernel. Per 16-edge tile per wave:
//   G = ew*(Z[src]-Z[dst]); S = ew*Z[dst]          (gathers from N*32 Zsm)
//   P^T = Wg^T @ G^T   (2 M-tiles x 2 K-steps)     -> C-layout == A-layout of mm2
//   T = tanh(P);  Zref = T_g @ Wg^T + T_s @ Ws^T   (2 N-tiles x 2 K-steps each)
//   atomicAdd Zref into Acc[src] (segment sum); write Zref rows e<NN (iters 0,1)
//   FINAL: Xref = T_g @ (Wg^T W_emb) + T_s @ (Ws^T W_emb), written to d_out
// ---------------------------------------------------------------------------
template<int FINAL>
__launch_bounds__(256)
__global__ void k_edge(const float* __restrict__ Zsm, const float* __restrict__ ew,
                       const int* __restrict__ srcI, const int* __restrict__ dstI,
                       const float* __restrict__ Wg, const float* __restrict__ Ws,
                       const float* __restrict__ WgEt, const float* __restrict__ WsEt,
                       float* __restrict__ Acc, float* __restrict__ ZrefSm,
                       float* __restrict__ Xref)
{
    const int lane = threadIdx.x & 63;
    const int u = lane & 15;
    const int q = lane >> 4;
    const int wave  = blockIdx.x * (blockDim.x >> 6) + (threadIdx.x >> 6);
    const int nwave = gridDim.x * (blockDim.x >> 6);

    // Weight fragments (loaded once per wave).
    // mm1 A-frag (tile h, K-step kk): A[m=u][k=16kk+4q+j] = Wg[k][16h+u]
    // mm2 B-frag (N-tile g==h, K-step kk): B[k][n=u] = Wg^T[j][16g+u] = Wg[16g+u][16kk+4q+j]
    hx4 WgA[2][2], WsA[2][2], WgB[2][2], WsB[2][2], WgC[2][2], WsC[2][2];
    for (int h = 0; h < 2; ++h)
        for (int kk = 0; kk < 2; ++kk) {
            hx4 a, b, c, d;
            for (int j = 0; j < 4; ++j) {
                int k = 16 * kk + 4 * q + j;
                a[j] = (_Float16)Wg[k * 32 + 16 * h + u];
                b[j] = (_Float16)Ws[k * 32 + 16 * h + u];
            }
            fx4 wg4 = *(const fx4*)&Wg[(16 * h + u) * 32 + 16 * kk + 4 * q];
            fx4 ws4 = *(const fx4*)&Ws[(16 * h + u) * 32 + 16 * kk + 4 * q];
            for (int j = 0; j < 4; ++j) { c[j] = (_Float16)wg4[j]; d[j] = (_Float16)ws4[j]; }
            WgA[h][kk] = a; WsA[h][kk] = b; WgB[h][kk] = c; WsB[h][kk] = d;
            if (FINAL) {
                fx4 e4 = *(const fx4*)&WgEt[(16 * h + u) * 32 + 16 * kk + 4 * q];
                fx4 f4 = *(const fx4*)&WsEt[(16 * h + u) * 32 + 16 * kk + 4 * q];
                hx4 g, hh;
                for (int j = 0; j < 4; ++j) { g[j] = (_Float16)e4[j]; hh[j] = (_Float16)f4[j]; }
                WgC[h][kk] = g; WsC[h][kk] = hh;
            }
        }

    const fx4 zero4 = {0.f, 0.f, 0.f, 0.f};
    const int ntile = NE / 16;

    for (int t = wave; t < ntile; t += nwave) {
        const int e0 = t * 16;
        const int e  = e0 + u;
        const int s  = srcI[e];
        const int d  = dstI[e];
        const float w = ew[e];

        const fx4 zs0 = *(const fx4*)&Zsm[s * 32 + 4 * q];
        const fx4 zs1 = *(const fx4*)&Zsm[s * 32 + 16 + 4 * q];
        const fx4 zd0 = *(const fx4*)&Zsm[d * 32 + 4 * q];
        const fx4 zd1 = *(const fx4*)&Zsm[d * 32 + 16 + 4 * q];

        hx4 Bg0, Bg1, Bs0, Bs1;
        for (int j = 0; j < 4; ++j) {
            Bg0[j] = (_Float16)(w * (zs0[j] - zd0[j]));
            Bg1[j] = (_Float16)(w * (zs1[j] - zd1[j]));
            Bs0[j] = (_Float16)(w * zd0[j]);
            Bs1[j] = (_Float16)(w * zd1[j]);
        }

        // mm1: P^T tiles (h) over K=32 (kk)
        fx4 P0 = MFMA(WgA[0][0], Bg0, zero4); P0 = MFMA(WgA[0][1], Bg1, P0);
        fx4 P1 = MFMA(WgA[1][0], Bg0, zero4); P1 = MFMA(WgA[1][1], Bg1, P1);
        fx4 S0 = MFMA(WsA[0][0], Bs0, zero4); S0 = MFMA(WsA[0][1], Bs1, S0);
        fx4 S1 = MFMA(WsA[1][0], Bs0, zero4); S1 = MFMA(WsA[1][1], Bs1, S1);

        hx4 Tg0, Tg1, Ts0, Ts1;
        for (int j = 0; j < 4; ++j) {
            Tg0[j] = (_Float16)ftanh(P0[j]);
            Tg1[j] = (_Float16)ftanh(P1[j]);
            Ts0[j] = (_Float16)ftanh(S0[j]);
            Ts1[j] = (_Float16)ftanh(S1[j]);
        }

        // mm2: Zref = T_g @ Wg^T + T_s @ Ws^T  (N-tiles g=0,1)
        fx4 Z0 = MFMA(Tg0, WgB[0][0], zero4);
        Z0 = MFMA(Tg1, WgB[0][1], Z0);
        Z0 = MFMA(Ts0, WsB[0][0], Z0);
        Z0 = MFMA(Ts1, WsB[0][1], Z0);
        fx4 Z1 = MFMA(Tg0, WgB[1][0], zero4);
        Z1 = MFMA(Tg1, WgB[1][1], Z1);
        Z1 = MFMA(Ts0, WsB[1][0], Z1);
        Z1 = MFMA(Ts1, WsB[1][1], Z1);

        // segment-sum scatter: lane holds Zref[e0+4q+r][16g+u]
        const int4 s4 = *(const int4*)&srcI[e0 + 4 * q];
        const int sarr[4] = {s4.x, s4.y, s4.z, s4.w};
        for (int r = 0; r < 4; ++r) {
            atomicAdd(&Acc[sarr[r] * 32 + u],      Z0[r]);
            atomicAdd(&Acc[sarr[r] * 32 + 16 + u], Z1[r]);
        }

        if (!FINAL) {
            if (e0 < NN) {  // NN % 16 == 0, whole-tile predicate
                for (int r = 0; r < 4; ++r) {
                    ZrefSm[(e0 + 4 * q + r) * 32 + u]      = Z0[r];
                    ZrefSm[(e0 + 4 * q + r) * 32 + 16 + u] = Z1[r];
                }
            }
        } else {
            fx4 X0 = MFMA(Tg0, WgC[0][0], zero4);
            X0 = MFMA(Tg1, WgC[0][1], X0);
            X0 = MFMA(Ts0, WsC[0][0], X0);
            X0 = MFMA(Ts1, WsC[0][1], X0);
            fx4 X1 = MFMA(Tg0, WgC[1][0], zero4);
            X1 = MFMA(Tg1, WgC[1][1], X1);
            X1 = MFMA(Ts0, WsC[1][0], X1);
            X1 = MFMA(Ts1, WsC[1][1], X1);
            for (int r = 0; r < 4; ++r) {
                Xref[(e0 + 4 * q + r) * 32 + u]      = X0[r];
                Xref[(e0 + 4 * q + r) * 32 + 16 + u] = X1[r];
            }
        }
    }
}

__global__ void k_zero(float* __restrict__ p, int n4) {
    int i = blockIdx.x * blockDim.x + threadIdx.x;
    if (i < n4) ((fx4*)p)[i] = (fx4){0.f, 0.f, 0.f, 0.f};
}

// WgEt = (Wg^T @ W_emb)^T, WsEt = (Ws^T @ W_emb)^T   (stored transposed for row loads)
__global__ void k_prep(const float* __restrict__ Wg, const float* __restrict__ Ws,
                       const float* __restrict__ We, float* __restrict__ WgEt,
                       float* __restrict__ WsEt) {
    for (int i = threadIdx.x; i < 1024; i += blockDim.x) {
        int c = i >> 5, j = i & 31;
        float a = 0.f, b = 0.f;
        for (int k = 0; k < 32; ++k) {
            a += Wg[k * 32 + j] * We[k * 32 + c];
            b += Ws[k * 32 + j] * We[k * 32 + c];
        }
        WgEt[c * 32 + j] = a;
        WsEt[c * 32 + j] = b;
    }
}

// Acc[src[e]] += xE[e]  (initial segment sum)
__global__ void k_seg0(const float* __restrict__ xE, const int* __restrict__ srcI,
                       float* __restrict__ Acc) {
    int i = blockIdx.x * blockDim.x + threadIdx.x;  // < NE*8
    int e = i >> 3, c4 = i & 7;
    fx4 v = ((const fx4*)xE)[i];
    int s = srcI[e];
    float* a = &Acc[s * 32 + c4 * 4];
    atomicAdd(a + 0, v[0]);
    atomicAdd(a + 1, v[1]);
    atomicAdd(a + 2, v[2]);
    atomicAdd(a + 3, v[3]);
}

__global__ void k_R(const float* __restrict__ Dm, const float* __restrict__ Acc,
                    float* __restrict__ R, float* __restrict__ Rout) {
    int i = blockIdx.x * blockDim.x + threadIdx.x;  // < NN*8
    if (i >= NN * 8) return;
    fx4 v = ((const fx4*)Dm)[i] - ((const fx4*)Acc)[i];
    ((fx4*)R)[i] = v;
    if (Rout) ((fx4*)Rout)[i] = v;
}

// Out[e] = Base[e] + ew[e]*(R[src[e]] - R[dst[e]])   for e < nE
__global__ void k_apply(const float* __restrict__ Base, const float* __restrict__ R,
                        const float* __restrict__ ew, const int* __restrict__ srcI,
                        const int* __restrict__ dstI, float* __restrict__ Out, int nE) {
    int i = blockIdx.x * blockDim.x + threadIdx.x;
    if (i >= nE * 8) return;
    int e = i >> 3, c4 = i & 7;
    float w = ew[e];
    int s = srcI[e], d = dstI[e];
    fx4 b  = ((const fx4*)Base)[i];
    fx4 rs = ((const fx4*)R)[s * 8 + c4];
    fx4 rd = ((const fx4*)R)[d * 8 + c4];
    fx4 o;
    for (int j = 0; j < 4; ++j) o[j] = b[j] + w * (rs[j] - rd[j]);
    ((fx4*)Out)[i] = o;
}

// RW = R @ W_emb
__global__ void k_rw(const float* __restrict__ R, const float* __restrict__ We,
                     float* __restrict__ RW) {
    __shared__ float sW[1024];
    for (int i = threadIdx.x; i < 1024; i += blockDim.x) sW[i] = We[i];
    __syncthreads();
    int t = blockIdx.x * blockDim.x + threadIdx.x;  // < NN*32
    if (t >= NN * 32) return;
    int n = t >> 5, c = t & 31;
    float acc = 0.f;
    const float* r = &R[n * 32];
    for (int k = 0; k < 32; ++k) acc += r[k] * sW[k * 32 + c];
    RW[t] = acc;
}

extern "C" void kernel_launch(void* const* d_in, const int* in_sizes, int n_in,
                              void* d_out, int out_size, void* d_ws, size_t ws_size,
                              hipStream_t stream) {
    (void)in_sizes; (void)n_in; (void)out_size; (void)ws_size;
    const float* Dm = (const float*)d_in[0];
    const float* xE = (const float*)d_in[1];
    const float* ew = (const float*)d_in[2];
    const float* Wg = (const float*)d_in[3];
    const float* Ws = (const float*)d_in[4];
    const float* We = (const float*)d_in[5];
    const int*   ei = (const int*)d_in[6];
    const int* srcI = ei;
    const int* dstI = ei + NE;

    float* X    = (float*)d_out;
    float* Xref = X + (size_t)NE * 32;
    float* Rout = Xref + (size_t)NE * 32;

    float* ws     = (float*)d_ws;
    float* Acc    = ws;                 // NN*32
    float* R      = Acc + NN * 32;      // NN*32
    float* ZsmA   = R + NN * 32;        // NN*32
    float* ZsmB   = ZsmA + NN * 32;     // NN*32
    float* ZrefSm = ZsmB + NN * 32;     // NN*32
    float* RW     = ZrefSm + NN * 32;   // NN*32
    float* WgEt   = RW + NN * 32;       // 1024
    float* WsEt   = WgEt + 1024;        // 1024

    const int n4N = NN * 8;             // fx4 count of node arrays
    dim3 B(256);

    hipLaunchKernelGGL(k_prep, dim3(1), B, 0, stream, Wg, Ws, We, WgEt, WsEt);

    // initial data_proj(xE)
    hipLaunchKernelGGL(k_zero, dim3(n4N / 256), B, 0, stream, Acc, n4N);
    hipLaunchKernelGGL(k_seg0, dim3(NE * 8 / 256), B, 0, stream, xE, srcI, Acc);
    hipLaunchKernelGGL(k_R, dim3(n4N / 256), B, 0, stream, Dm, Acc, R, (float*)nullptr);
    hipLaunchKernelGGL(k_apply, dim3(NN * 8 / 256), B, 0, stream, xE, R, ew, srcI, dstI,
                       ZsmA, NN);

    const float* zin = ZsmA;
    float* zout = ZsmB;
    for (int it = 0; it < 3; ++it) {
        hipLaunchKernelGGL(k_zero, dim3(n4N / 256), B, 0, stream, Acc, n4N);
        if (it < 2) {
            hipLaunchKernelGGL(k_edge<0>, dim3(1024), B, 0, stream, zin, ew, srcI, dstI,
                               Wg, Ws, WgEt, WsEt, Acc, ZrefSm, (float*)nullptr);
            hipLaunchKernelGGL(k_R, dim3(n4N / 256), B, 0, stream, Dm, Acc, R,
                               (float*)nullptr);
            hipLaunchKernelGGL(k_apply, dim3(NN * 8 / 256), B, 0, stream, ZrefSm, R, ew,
                               srcI, dstI, zout, NN);
            const float* tmp = zin; zin = zout; zout = (float*)tmp;
        } else {
            hipLaunchKernelGGL(k_edge<1>, dim3(1024), B, 0, stream, zin, ew, srcI, dstI,
                               Wg, Ws, WgEt, WsEt, Acc, (float*)nullptr, Xref);
            hipLaunchKernelGGL(k_R, dim3(n4N / 256), B, 0, stream, Dm, Acc, R, Rout);
            hipLaunchKernelGGL(k_rw, dim3(NN * 32 / 256), B, 0, stream, R, We, RW);
            hipLaunchKernelGGL(k_apply, dim3(NE * 8 / 256), B, 0, stream, Xref, RW, ew,
                               srcI, dstI, X, NE);
        }
    }
}

// Round 2
// 1407.950 us; speedup vs baseline: 1.2739x; 1.2739x over previous
//
#include <hip/hip_runtime.h>

#define NN 100000
#define NE 1600000
#define NBLK_SCAN 98   // ceil(NN/1024)

typedef __attribute__((ext_vector_type(4))) float   fx4;
typedef __attribute__((ext_vector_type(4))) _Float16 hx4;

__device__ __forceinline__ float ftanh(float x) {
    float t = __expf(2.0f * x);
    return 1.0f - 2.0f * __builtin_amdgcn_rcpf(t + 1.0f);
}

#define MFMA(a, b, c) __builtin_amdgcn_mfma_f32_16x16x16f16((a), (b), (c), 0, 0, 0)

// ---------------------------------------------------------------------------
// Edge kernel. Per 16-edge tile per wave:
//   G = ew*(Z[src]-Z[dst]); S = ew*Z[dst]       (gathers from N*32 Zsm, LLC-hot)
//   P^T = Wg^T @ G^T  -> C-layout == A-layout of mm2 (zero-shuffle chaining)
//   T = tanh(P);  Zref = T_g @ Wg^T + T_s @ Ws^T
//   write Zref row to CSR slot (ZrefPerm) for the contiguous segment-reduce;
//   iters 0,1: also write Zref rows e<NN (next data_proj input)
//   FINAL: Xref = T_g @ (Wg^T W_emb) + T_s @ (Ws^T W_emb) -> d_out
// ---------------------------------------------------------------------------
template<int FINAL>
__launch_bounds__(256)
__global__ void k_edge(const float* __restrict__ Zsm, const float* __restrict__ ew,
                       const int* __restrict__ srcI, const int* __restrict__ dstI,
                       const int* __restrict__ slot,
                       const float* __restrict__ Wg, const float* __restrict__ Ws,
                       const float* __restrict__ WgEt, const float* __restrict__ WsEt,
                       float* __restrict__ ZrefPerm, float* __restrict__ ZrefSm,
                       float* __restrict__ Xref)
{
    const int lane = threadIdx.x & 63;
    const int u = lane & 15;
    const int q = lane >> 4;
    const int wave  = blockIdx.x * (blockDim.x >> 6) + (threadIdx.x >> 6);
    const int nwave = gridDim.x * (blockDim.x >> 6);

    hx4 WgA[2][2], WsA[2][2], WgB[2][2], WsB[2][2], WgC[2][2], WsC[2][2];
    for (int h = 0; h < 2; ++h)
        for (int kk = 0; kk < 2; ++kk) {
            hx4 a, b, c, d;
            for (int j = 0; j < 4; ++j) {
                int k = 16 * kk + 4 * q + j;
                a[j] = (_Float16)Wg[k * 32 + 16 * h + u];
                b[j] = (_Float16)Ws[k * 32 + 16 * h + u];
            }
            fx4 wg4 = *(const fx4*)&Wg[(16 * h + u) * 32 + 16 * kk + 4 * q];
            fx4 ws4 = *(const fx4*)&Ws[(16 * h + u) * 32 + 16 * kk + 4 * q];
            for (int j = 0; j < 4; ++j) { c[j] = (_Float16)wg4[j]; d[j] = (_Float16)ws4[j]; }
            WgA[h][kk] = a; WsA[h][kk] = b; WgB[h][kk] = c; WsB[h][kk] = d;
            if (FINAL) {
                fx4 e4 = *(const fx4*)&WgEt[(16 * h + u) * 32 + 16 * kk + 4 * q];
                fx4 f4 = *(const fx4*)&WsEt[(16 * h + u) * 32 + 16 * kk + 4 * q];
                hx4 g, hh;
                for (int j = 0; j < 4; ++j) { g[j] = (_Float16)e4[j]; hh[j] = (_Float16)f4[j]; }
                WgC[h][kk] = g; WsC[h][kk] = hh;
            }
        }

    const fx4 zero4 = {0.f, 0.f, 0.f, 0.f};
    const int ntile = NE / 16;

    for (int t = wave; t < ntile; t += nwave) {
        const int e0 = t * 16;
        const int e  = e0 + u;
        const int s  = srcI[e];
        const int d  = dstI[e];
        const float w = ew[e];

        const fx4 zs0 = *(const fx4*)&Zsm[s * 32 + 4 * q];
        const fx4 zs1 = *(const fx4*)&Zsm[s * 32 + 16 + 4 * q];
        const fx4 zd0 = *(const fx4*)&Zsm[d * 32 + 4 * q];
        const fx4 zd1 = *(const fx4*)&Zsm[d * 32 + 16 + 4 * q];

        hx4 Bg0, Bg1, Bs0, Bs1;
        for (int j = 0; j < 4; ++j) {
            Bg0[j] = (_Float16)(w * (zs0[j] - zd0[j]));
            Bg1[j] = (_Float16)(w * (zs1[j] - zd1[j]));
            Bs0[j] = (_Float16)(w * zd0[j]);
            Bs1[j] = (_Float16)(w * zd1[j]);
        }

        fx4 P0 = MFMA(WgA[0][0], Bg0, zero4); P0 = MFMA(WgA[0][1], Bg1, P0);
        fx4 P1 = MFMA(WgA[1][0], Bg0, zero4); P1 = MFMA(WgA[1][1], Bg1, P1);
        fx4 S0 = MFMA(WsA[0][0], Bs0, zero4); S0 = MFMA(WsA[0][1], Bs1, S0);
        fx4 S1 = MFMA(WsA[1][0], Bs0, zero4); S1 = MFMA(WsA[1][1], Bs1, S1);

        hx4 Tg0, Tg1, Ts0, Ts1;
        for (int j = 0; j < 4; ++j) {
            Tg0[j] = (_Float16)ftanh(P0[j]);
            Tg1[j] = (_Float16)ftanh(P1[j]);
            Ts0[j] = (_Float16)ftanh(S0[j]);
            Ts1[j] = (_Float16)ftanh(S1[j]);
        }

        fx4 Z0 = MFMA(Tg0, WgB[0][0], zero4);
        Z0 = MFMA(Tg1, WgB[0][1], Z0);
        Z0 = MFMA(Ts0, WsB[0][0], Z0);
        Z0 = MFMA(Ts1, WsB[0][1], Z0);
        fx4 Z1 = MFMA(Tg0, WgB[1][0], zero4);
        Z1 = MFMA(Tg1, WgB[1][1], Z1);
        Z1 = MFMA(Ts0, WsB[1][0], Z1);
        Z1 = MFMA(Ts1, WsB[1][1], Z1);

        // CSR scatter: lane holds Zref[e0+4q+r][16g+u] -> row slot[e0+4q+r]
        const int4 sl4 = *(const int4*)&slot[e0 + 4 * q];
        const int sl[4] = {sl4.x, sl4.y, sl4.z, sl4.w};
        for (int r = 0; r < 4; ++r) {
            ZrefPerm[sl[r] * 32 + u]      = Z0[r];
            ZrefPerm[sl[r] * 32 + 16 + u] = Z1[r];
        }

        if (!FINAL) {
            if (e0 < NN) {  // NN % 16 == 0
                for (int r = 0; r < 4; ++r) {
                    ZrefSm[(e0 + 4 * q + r) * 32 + u]      = Z0[r];
                    ZrefSm[(e0 + 4 * q + r) * 32 + 16 + u] = Z1[r];
                }
            }
        } else {
            fx4 X0 = MFMA(Tg0, WgC[0][0], zero4);
            X0 = MFMA(Tg1, WgC[0][1], X0);
            X0 = MFMA(Ts0, WsC[0][0], X0);
            X0 = MFMA(Ts1, WsC[0][1], X0);
            fx4 X1 = MFMA(Tg0, WgC[1][0], zero4);
            X1 = MFMA(Tg1, WgC[1][1], X1);
            X1 = MFMA(Ts0, WsC[1][0], X1);
            X1 = MFMA(Ts1, WsC[1][1], X1);
            for (int r = 0; r < 4; ++r) {
                Xref[(e0 + 4 * q + r) * 32 + u]      = X0[r];
                Xref[(e0 + 4 * q + r) * 32 + 16 + u] = X1[r];
            }
        }
    }
}

// ---------------- CSR construction ----------------
__global__ void k_zero_i(int* __restrict__ p, int n) {
    int i = blockIdx.x * blockDim.x + threadIdx.x;
    if (i < n) p[i] = 0;
}

__global__ void k_hist(const int* __restrict__ src, int* __restrict__ cnt) {
    int e = blockIdx.x * blockDim.x + threadIdx.x;
    if (e < NE) atomicAdd(&cnt[src[e]], 1);
}

// per-block (1024-elem chunk) sums
__global__ void k_scanA(const int* __restrict__ cnt, int* __restrict__ blksum) {
    __shared__ int sd[256];
    int b = blockIdx.x, t = threadIdx.x;
    int base = b * 1024 + t * 4;
    int s = 0;
    for (int j = 0; j < 4; ++j) { int idx = base + j; if (idx < NN) s += cnt[idx]; }
    sd[t] = s; __syncthreads();
    for (int off = 128; off > 0; off >>= 1) {
        if (t < off) sd[t] += sd[t + off];
        __syncthreads();
    }
    if (t == 0) blksum[b] = sd[0];
}

// exclusive scan of block sums (single block, nblk <= 128)
__global__ void k_scanB(int* __restrict__ blksum) {
    __shared__ int s[128];
    int t = threadIdx.x;
    s[t] = (t < NBLK_SCAN) ? blksum[t] : 0;
    __syncthreads();
    for (int off = 1; off < 128; off <<= 1) {
        int x = (t >= off) ? s[t - off] : 0;
        __syncthreads();
        s[t] += x;
        __syncthreads();
    }
    if (t < NBLK_SCAN) blksum[t] = (t == 0) ? 0 : s[t - 1];
}

// full exclusive scan -> rowptr, cur
__global__ void k_scanC(const int* __restrict__ cnt, const int* __restrict__ blksum,
                        int* __restrict__ rowptr, int* __restrict__ cur) {
    __shared__ int sth[256];
    int b = blockIdx.x, t = threadIdx.x;
    int base = b * 1024 + t * 4;
    int v[4]; int s = 0;
    for (int j = 0; j < 4; ++j) { int idx = base + j; v[j] = (idx < NN) ? cnt[idx] : 0; s += v[j]; }
    sth[t] = s; __syncthreads();
    for (int off = 1; off < 256; off <<= 1) {
        int x = (t >= off) ? sth[t - off] : 0;
        __syncthreads();
        sth[t] += x;
        __syncthreads();
    }
    int excl = ((t == 0) ? 0 : sth[t - 1]) + blksum[b];
    for (int j = 0; j < 4; ++j) {
        int idx = base + j;
        if (idx < NN) { rowptr[idx] = excl; cur[idx] = excl; excl += v[j]; }
    }
    if (b == 0 && t == 0) rowptr[NN] = NE;
}

__global__ void k_fill(const int* __restrict__ src, int* __restrict__ cur,
                       int* __restrict__ slot, int* __restrict__ eidx) {
    int e = blockIdx.x * blockDim.x + threadIdx.x;
    if (e < NE) {
        int p = atomicAdd(&cur[src[e]], 1);
        slot[e] = p;
        eidx[p] = e;
    }
}

// ---------------- segment reduce (CSR ranges), fused R = D - sum ----------------
// eidx != nullptr: gather F[eidx[i]]; else F rows are already in slot order.
__global__ void k_reduce(const float* __restrict__ F, const int* __restrict__ eidx,
                         const int* __restrict__ rowptr, const float* __restrict__ Dm,
                         float* __restrict__ R, float* __restrict__ Rout) {
    int t = blockIdx.x * blockDim.x + threadIdx.x;  // NN*8
    if (t >= NN * 8) return;
    int n = t >> 3, c4 = (t & 7) * 4;
    int b0 = rowptr[n], b1 = rowptr[n + 1];
    fx4 s = {0.f, 0.f, 0.f, 0.f};
    if (eidx) {
        for (int i = b0; i < b1; ++i) s += *(const fx4*)&F[eidx[i] * 32 + c4];
    } else {
        for (int i = b0; i < b1; ++i) s += *(const fx4*)&F[i * 32 + c4];
    }
    fx4 r = ((const fx4*)Dm)[t] - s;
    ((fx4*)R)[t] = r;
    if (Rout) ((fx4*)Rout)[t] = r;
}

// WgEt = (Wg^T @ W_emb)^T, WsEt = (Ws^T @ W_emb)^T
__global__ void k_prep(const float* __restrict__ Wg, const float* __restrict__ Ws,
                       const float* __restrict__ We, float* __restrict__ WgEt,
                       float* __restrict__ WsEt) {
    for (int i = threadIdx.x; i < 1024; i += blockDim.x) {
        int c = i >> 5, j = i & 31;
        float a = 0.f, b = 0.f;
        for (int k = 0; k < 32; ++k) {
            a += Wg[k * 32 + j] * We[k * 32 + c];
            b += Ws[k * 32 + j] * We[k * 32 + c];
        }
        WgEt[c * 32 + j] = a;
        WsEt[c * 32 + j] = b;
    }
}

// Out[e] = Base[e] + ew[e]*(R[src[e]] - R[dst[e]])
__global__ void k_apply(const float* __restrict__ Base, const float* __restrict__ R,
                        const float* __restrict__ ew, const int* __restrict__ srcI,
                        const int* __restrict__ dstI, float* __restrict__ Out, int nE) {
    int i = blockIdx.x * blockDim.x + threadIdx.x;
    if (i >= nE * 8) return;
    int e = i >> 3, c4 = i & 7;
    float w = ew[e];
    int s = srcI[e], d = dstI[e];
    fx4 b  = ((const fx4*)Base)[i];
    fx4 rs = ((const fx4*)R)[s * 8 + c4];
    fx4 rd = ((const fx4*)R)[d * 8 + c4];
    fx4 o;
    for (int j = 0; j < 4; ++j) o[j] = b[j] + w * (rs[j] - rd[j]);
    ((fx4*)Out)[i] = o;
}

// RW = R @ W_emb
__global__ void k_rw(const float* __restrict__ R, const float* __restrict__ We,
                     float* __restrict__ RW) {
    __shared__ float sW[1024];
    for (int i = threadIdx.x; i < 1024; i += blockDim.x) sW[i] = We[i];
    __syncthreads();
    int t = blockIdx.x * blockDim.x + threadIdx.x;
    if (t >= NN * 32) return;
    int n = t >> 5, c = t & 31;
    float acc = 0.f;
    const float* r = &R[n * 32];
    for (int k = 0; k < 32; ++k) acc += r[k] * sW[k * 32 + c];
    RW[t] = acc;
}

extern "C" void kernel_launch(void* const* d_in, const int* in_sizes, int n_in,
                              void* d_out, int out_size, void* d_ws, size_t ws_size,
                              hipStream_t stream) {
    (void)in_sizes; (void)n_in; (void)out_size; (void)ws_size;
    const float* Dm = (const float*)d_in[0];
    const float* xE = (const float*)d_in[1];
    const float* ew = (const float*)d_in[2];
    const float* Wg = (const float*)d_in[3];
    const float* Ws = (const float*)d_in[4];
    const float* We = (const float*)d_in[5];
    const int*   ei = (const int*)d_in[6];
    const int* srcI = ei;
    const int* dstI = ei + NE;

    float* X    = (float*)d_out;
    float* Xref = X + (size_t)NE * 32;
    float* Rout = Xref + (size_t)NE * 32;

    // X region of d_out is dead until the last kernel -> use as ZrefPerm scratch.
    float* ZrefPerm = X;

    float* ws     = (float*)d_ws;
    float* R      = ws;                 // NN*32
    float* ZsmA   = R + NN * 32;        // NN*32
    float* ZsmB   = ZsmA + NN * 32;     // NN*32
    float* ZrefSm = ZsmB + NN * 32;     // NN*32
    float* RW     = ZrefSm + NN * 32;   // NN*32
    float* WgEt   = RW + NN * 32;       // 1024
    float* WsEt   = WgEt + 1024;        // 1024
    int*   cnt    = (int*)(WsEt + 1024);// NN
    int*   rowptr = cnt + NN;           // NN+1
    int*   cur    = rowptr + NN + 1;    // NN
    int*   blksum = cur + NN;           // 128
    int*   slot   = blksum + 128;       // NE
    int*   eidx   = slot + NE;          // NE

    dim3 B(256);
    const int gE = (NE + 255) / 256;

    hipLaunchKernelGGL(k_prep, dim3(1), B, 0, stream, Wg, Ws, We, WgEt, WsEt);

    // CSR build (once per launch)
    hipLaunchKernelGGL(k_zero_i, dim3((NN + 255) / 256), B, 0, stream, cnt, NN);
    hipLaunchKernelGGL(k_hist, dim3(gE), B, 0, stream, srcI, cnt);
    hipLaunchKernelGGL(k_scanA, dim3(NBLK_SCAN), B, 0, stream, cnt, blksum);
    hipLaunchKernelGGL(k_scanB, dim3(1), dim3(128), 0, stream, blksum);
    hipLaunchKernelGGL(k_scanC, dim3(NBLK_SCAN), B, 0, stream, cnt, blksum, rowptr, cur);
    hipLaunchKernelGGL(k_fill, dim3(gE), B, 0, stream, srcI, cur, slot, eidx);

    // initial data_proj(xE): R = D - seg(xE); Z[0:NN] = xE + grad(R)
    hipLaunchKernelGGL(k_reduce, dim3(NN * 8 / 256 + 1), B, 0, stream, xE, eidx, rowptr,
                       Dm, R, (float*)nullptr);
    hipLaunchKernelGGL(k_apply, dim3(NN * 8 / 256), B, 0, stream, xE, R, ew, srcI, dstI,
                       ZsmA, NN);

    const float* zin = ZsmA;
    float* zout = ZsmB;
    for (int it = 0; it < 3; ++it) {
        if (it < 2) {
            hipLaunchKernelGGL(k_edge<0>, dim3(1024), B, 0, stream, zin, ew, srcI, dstI,
                               slot, Wg, Ws, WgEt, WsEt, ZrefPerm, ZrefSm,
                               (float*)nullptr);
            hipLaunchKernelGGL(k_reduce, dim3(NN * 8 / 256 + 1), B, 0, stream, ZrefPerm,
                               (const int*)nullptr, rowptr, Dm, R, (float*)nullptr);
            hipLaunchKernelGGL(k_apply, dim3(NN * 8 / 256), B, 0, stream, ZrefSm, R, ew,
                               srcI, dstI, zout, NN);
            const float* tmp = zin; zin = zout; zout = (float*)tmp;
        } else {
            hipLaunchKernelGGL(k_edge<1>, dim3(1024), B, 0, stream, zin, ew, srcI, dstI,
                               slot, Wg, Ws, WgEt, WsEt, ZrefPerm, (float*)nullptr, Xref);
            hipLaunchKernelGGL(k_reduce, dim3(NN * 8 / 256 + 1), B, 0, stream, ZrefPerm,
                               (const int*)nullptr, rowptr, Dm, R, Rout);
            hipLaunchKernelGGL(k_rw, dim3(NN * 32 / 256 + 1), B, 0, stream, R, We, RW);
            hipLaunchKernelGGL(k_apply, dim3(NE * 8 / 256), B, 0, stream, Xref, RW, ew,
                               srcI, dstI, X, NE);
        }
    }
}